// Round 5
// baseline (112.258 us; speedup 1.0000x reference)
//
#include <hip/hip_runtime.h>
#include <cstdint>

// 4-layer MLP: [B,64] -> 4 -> 8 -> 8 -> 32, sigmoid each layer. All f32.
// HBM floor: 256 MB read + 128 MB write -> ~61 us @ 6.3 TB/s achievable.
//
// R1 (145us): per-thread row reads -> L1 line amplification, no MLP.
// R2 (184us): VGPR-roundtrip LDS tile + block barriers -> serialized staging.
// R3 (95us):  wave-local global_load_lds + vmcnt(0), but serial per tile.
// R4 (104us): persistent pipeline, BUT (a) weights via global loads polluted
//             the vmem queue, (b) loop-top vmcnt(0) waited on prior stores ->
//             store-drain serialization every iteration.
// R5: weights back in LDS (broadcast ds_read, lgkm counter — vmcnt queue holds
//     ONLY 16 prefetch loads + 8 stores). Counted wait vmcnt(8): retires the
//     16 loads (older), leaves the 8 stores (newer) in flight. Never drain to
//     0 in the loop (T4).

#define IN_DIM 64
#define OUT_DIM 32
#define THREADS 256
#define WAVES_PER_BLOCK 4
#define ROWS_PER_WAVE 64
#define GRID_BLOCKS 512

__device__ __forceinline__ float fast_sigmoid(float z) {
    float e = __expf(-z);
    return __builtin_amdgcn_rcpf(1.0f + e);
}

__global__ __launch_bounds__(THREADS) void mlp4_kernel(
    const float* __restrict__ x,
    const float* __restrict__ W0, const float* __restrict__ b0,
    const float* __restrict__ W1, const float* __restrict__ b1,
    const float* __restrict__ W2, const float* __restrict__ b2,
    const float* __restrict__ W3, const float* __restrict__ b3,
    float* __restrict__ out, int batch)
{
    // Per-wave x tile: 64 rows x 16 float4 = 16 KB; 4 waves = 64 KB.
    __shared__ float4 sx[WAVES_PER_BLOCK * 1024];
    // Weights/biases in LDS (~2.6 KB): broadcast reads, conflict-free.
    __shared__ float sW0[4 * 64];
    __shared__ float sb0[4];
    __shared__ float sW1[8 * 4];
    __shared__ float sb1[8];
    __shared__ float sW2[8 * 8];
    __shared__ float sb2[8];
    __shared__ float sW3[32 * 8];
    __shared__ float sb3[32];

    const int tid  = threadIdx.x;
    const int wave = tid >> 6;
    const int lane = tid & 63;

    sW0[tid] = W0[tid];
    sW3[tid] = W3[tid];
    if (tid < 64) sW2[tid] = W2[tid];
    if (tid < 32) { sW1[tid] = W1[tid]; sb3[tid] = b3[tid]; }
    if (tid < 8)  { sb1[tid] = b1[tid]; sb2[tid] = b2[tid]; }
    if (tid < 4)  { sb0[tid] = b0[tid]; }
    __syncthreads();   // only block barrier in the kernel

    const long long gw        = (long long)blockIdx.x * WAVES_PER_BLOCK + wave;
    const long long rowStride = (long long)GRID_BLOCKS * WAVES_PER_BLOCK * ROWS_PER_WAVE;
    const long long row0      = gw * ROWS_PER_WAVE;
    if (row0 >= batch) return;   // wave-uniform

    const float4* xg    = reinterpret_cast<const float4*>(x);
    const int     wbase = wave << 10;

    // 16x global_load_lds (1 KB each). Linear LDS dest (HW: base + lane*16);
    // readback bank-balance via XOR-pre-swizzled GLOBAL source: slot
    // p=(r<<4)|c' holds chunk c'^(r&15) of row r (permutation inside one
    // contiguous 256 B row -> coalescing preserved).
    auto issue = [&](long long rowT) {
        #pragma unroll
        for (int k = 0; k < 16; ++k) {
            const int p = (k << 6) | lane;
            const int r = p >> 4;
            const int c = (p & 15) ^ (r & 15);
            long long row = rowT + r;
            if (row >= batch) row = batch - 1;   // never triggers (batch%64==0)
            __builtin_amdgcn_global_load_lds(
                reinterpret_cast<const uint32_t*>(xg + row * 16 + c),
                reinterpret_cast<uint32_t*>(&sx[wbase + (k << 6)]),
                16, 0, 0);
        }
    };

    const int myBase = wbase | (lane << 4);
    const int rx     = lane & 15;
    float4 xr[16];

    // ---- Prologue: stage tile0, copy to regs, launch tile1 ----
    issue(row0);
    asm volatile("s_waitcnt vmcnt(0)" ::: "memory");
    __builtin_amdgcn_sched_barrier(0);
    #pragma unroll
    for (int c = 0; c < 16; ++c) xr[c] = sx[myBase | (c ^ rx)];
    asm volatile("s_waitcnt lgkmcnt(0)" ::: "memory");
    __builtin_amdgcn_sched_barrier(0);
    if (row0 + rowStride < batch) issue(row0 + rowStride);

    for (long long r0 = row0; r0 < batch; r0 += rowStride) {
        // ---- Layer 0: 64 -> 4 ----
        float acc[4] = {sb0[0], sb0[1], sb0[2], sb0[3]};
        #pragma unroll
        for (int c = 0; c < 16; ++c) {
            const float4 xv = xr[c];
            #pragma unroll
            for (int o = 0; o < 4; ++o) {
                const float4 wv = *reinterpret_cast<const float4*>(&sW0[o * 64 + 4 * c]);
                acc[o] = fmaf(xv.x, wv.x, acc[o]);
                acc[o] = fmaf(xv.y, wv.y, acc[o]);
                acc[o] = fmaf(xv.z, wv.z, acc[o]);
                acc[o] = fmaf(xv.w, wv.w, acc[o]);
            }
        }
        float h0[4];
        #pragma unroll
        for (int o = 0; o < 4; ++o) h0[o] = fast_sigmoid(acc[o]);

        // ---- Layer 1: 4 -> 8 ----
        float h1[8];
        #pragma unroll
        for (int j = 0; j < 8; ++j) {
            float a = sb1[j];
            #pragma unroll
            for (int c = 0; c < 4; ++c) a = fmaf(h0[c], sW1[j * 4 + c], a);
            h1[j] = fast_sigmoid(a);
        }

        // ---- Layer 2: 8 -> 8 ----
        float h2[8];
        #pragma unroll
        for (int j = 0; j < 8; ++j) {
            float a = sb2[j];
            #pragma unroll
            for (int i = 0; i < 8; ++i) a = fmaf(h1[i], sW2[j * 8 + i], a);
            h2[j] = fast_sigmoid(a);
        }

        // ---- Layer 3: 8 -> 32, 8x float4 stores (fire-and-forget) ----
        {
            const long long row = r0 + lane;
            float4* op = reinterpret_cast<float4*>(out + (size_t)row * OUT_DIM);
            #pragma unroll
            for (int q = 0; q < OUT_DIM / 4; ++q) {
                float o4[4];
                #pragma unroll
                for (int r2 = 0; r2 < 4; ++r2) {
                    const int oidx = q * 4 + r2;
                    float a = sb3[oidx];
                    #pragma unroll
                    for (int j = 0; j < 8; ++j)
                        a = fmaf(h2[j], sW3[oidx * 8 + j], a);
                    o4[r2] = fast_sigmoid(a);
                }
                op[q] = make_float4(o4[0], o4[1], o4[2], o4[3]);
            }
        }

        // ---- Pipeline advance: wait ONLY for the 16 prefetch loads ----
        const long long rn = r0 + rowStride;
        if (rn < batch) {
            // vmem queue (oldest->newest): 16 loads(tile rn), 8 stores(just
            // issued). vmcnt(8) retires the loads, leaves stores in flight.
            asm volatile("s_waitcnt vmcnt(8)" ::: "memory");
            __builtin_amdgcn_sched_barrier(0);
            #pragma unroll
            for (int c = 0; c < 16; ++c) xr[c] = sx[myBase | (c ^ rx)];
            asm volatile("s_waitcnt lgkmcnt(0)" ::: "memory");
            __builtin_amdgcn_sched_barrier(0);
            const long long rnn = rn + rowStride;
            if (rnn < batch) issue(rnn);
        }
    }
}

extern "C" void kernel_launch(void* const* d_in, const int* in_sizes, int n_in,
                              void* d_out, int out_size, void* d_ws, size_t ws_size,
                              hipStream_t stream) {
    const float* x  = (const float*)d_in[0];
    const float* W0 = (const float*)d_in[1];
    const float* b0 = (const float*)d_in[2];
    const float* W1 = (const float*)d_in[3];
    const float* b1 = (const float*)d_in[4];
    const float* W2 = (const float*)d_in[5];
    const float* b2 = (const float*)d_in[6];
    const float* W3 = (const float*)d_in[7];
    const float* b3 = (const float*)d_in[8];
    float* out = (float*)d_out;

    const int batch = in_sizes[0] / IN_DIM;  // 1,000,000

    mlp4_kernel<<<GRID_BLOCKS, THREADS, 0, stream>>>(x, W0, b0, W1, b1,
                                                     W2, b2, W3, b3, out, batch);
}

// Round 7
// 103.545 us; speedup vs baseline: 1.0841x; 1.0841x over previous
//
#include <hip/hip_runtime.h>
#include <cstdint>

// 4-layer MLP: [B,64] -> 4 -> 8 -> 8 -> 32, sigmoid each layer. All f32.
//
// R1 (145us): per-thread row reads -> L1 line amplification.
// R2 (184us): VGPR-roundtrip LDS tile + block barriers.
// R3 (95us):  wave-local global_load_lds(16B) + vmcnt(0); best so far.
// R4 (104us): persistent pipeline; weight loads polluted vmem queue +
//             loop-top vmcnt(0) waited on stores.
// R5 (112us): counted vmcnt(8) pipeline — still latency-bound; HBM 0.9 TB/s,
//             VALU 20%, occ 19%. Lesson: per-wave MLP is queue-capped; the
//             fill kernel (7.2 TB/s @ 10% occ) wins on TLP + dispatch churn.
// R6: back to R3's non-persistent shape, double the waves: 512-thread
//     blocks, 8 waves, 32-row (8 KB) tile per wave, 2 lanes per row.
//     16 waves/CU, 3907 blocks (dynamic balancing), finer stall granularity.
//     Nontemporal stores keep out-traffic from evicting x's L3 residency.
//     (R6 first attempt failed to compile: __builtin_nontemporal_store needs
//     a clang ext_vector pointer, not HIP_vector_type<float,4>*.)

#define IN_DIM 64
#define OUT_DIM 32
#define THREADS 512
#define WAVES_PER_BLOCK 8
#define ROWS_PER_WAVE 32
#define ROWS_PER_BLOCK (WAVES_PER_BLOCK * ROWS_PER_WAVE)   // 256

typedef float v4f __attribute__((ext_vector_type(4)));

__device__ __forceinline__ float fast_sigmoid(float z) {
    float e = __expf(-z);
    return __builtin_amdgcn_rcpf(1.0f + e);
}

__global__ __launch_bounds__(THREADS) void mlp4_kernel(
    const float* __restrict__ x,
    const float* __restrict__ W0, const float* __restrict__ b0,
    const float* __restrict__ W1, const float* __restrict__ b1,
    const float* __restrict__ W2, const float* __restrict__ b2,
    const float* __restrict__ W3, const float* __restrict__ b3,
    float* __restrict__ out, int batch)
{
    // Per-wave x tile: 32 rows x 16 float4 = 8 KB; 8 waves = 64 KB.
    __shared__ float4 sx[WAVES_PER_BLOCK * 512];
    // Weights/biases (~2.6 KB), broadcast ds_reads (<=2-way addr variety = free).
    __shared__ float sW0[4 * 64];
    __shared__ float sb0[4];
    __shared__ float sW1[8 * 4];
    __shared__ float sb1[8];
    __shared__ float sW2[8 * 8];
    __shared__ float sb2[8];
    __shared__ float sW3[32 * 8];
    __shared__ float sb3[32];

    const int tid = threadIdx.x;
    if (tid < 256) { sW0[tid] = W0[tid]; sW3[tid] = W3[tid]; }
    if (tid < 64)  { sW2[tid] = W2[tid]; }
    if (tid < 32)  { sW1[tid] = W1[tid]; sb3[tid] = b3[tid]; }
    if (tid < 8)   { sb1[tid] = b1[tid]; sb2[tid] = b2[tid]; }
    if (tid < 4)   { sb0[tid] = b0[tid]; }
    __syncthreads();   // only block barrier

    const int wave = tid >> 6;
    const int lane = tid & 63;
    const long long row0 =
        (long long)blockIdx.x * ROWS_PER_BLOCK + wave * ROWS_PER_WAVE;
    if (row0 >= batch) return;   // wave-uniform

    const float4* xg    = reinterpret_cast<const float4*>(x);
    const int     wbase = wave << 9;   // 512 float4 slots per wave

    // ---- Stage 32 rows: 8x global_load_lds (1 KB each). Linear LDS dest
    // (HW: base + lane*16). Readback bank balance via XOR-pre-swizzled
    // GLOBAL source: slot p=(r<<4)|c' holds chunk c'^(r&7) of row r — a
    // permutation within one contiguous 256 B row, so each instr still
    // reads 1 KB contiguous (4 whole rows).
    #pragma unroll
    for (int k = 0; k < 8; ++k) {
        const int p = (k << 6) | lane;
        const int r = p >> 4;
        const int c = (p & 15) ^ (r & 7);
        long long row = row0 + r;
        if (row >= batch) row = batch - 1;   // clamp (tail block only)
        __builtin_amdgcn_global_load_lds(
            reinterpret_cast<const uint32_t*>(xg + row * 16 + c),
            reinterpret_cast<uint32_t*>(&sx[wbase + (k << 6)]),
            16, 0, 0);
    }
    asm volatile("s_waitcnt vmcnt(0)" ::: "memory");
    __builtin_amdgcn_sched_barrier(0);

    // ---- 2 lanes per row: lane pair (2r, 2r+1) owns local row r ----
    const int r = lane >> 1;     // local row 0..31
    const int h = lane & 1;      // which half of the row (32 cols each)

    // Read my 8 chunks (cols 32h..32h+31). Slot (r<<4)|(c^(r&7)):
    // bank-group = j ^ (r&7) -> 8 lanes per 4-bank group per instr (balanced).
    float4 xv[8];
    #pragma unroll
    for (int j = 0; j < 8; ++j) {
        const int c = (h << 3) | j;
        xv[j] = sx[wbase + (r << 4) + (c ^ (r & 7))];
    }

    // ---- Layer 0: 64 -> 4, split across the lane pair ----
    const float4* w0v = reinterpret_cast<const float4*>(sW0);
    float po[4];
    #pragma unroll
    for (int o = 0; o < 4; ++o) {
        float a = 0.f;
        #pragma unroll
        for (int j = 0; j < 8; ++j) {
            const float4 wv = w0v[o * 16 + (h << 3) + j];
            a = fmaf(xv[j].x, wv.x, a);
            a = fmaf(xv[j].y, wv.y, a);
            a = fmaf(xv[j].z, wv.z, a);
            a = fmaf(xv[j].w, wv.w, a);
        }
        po[o] = a;
    }
    float h0[4];
    #pragma unroll
    for (int o = 0; o < 4; ++o) {
        const float sum = po[o] + __shfl_xor(po[o], 1, 64);  // pair-reduce
        h0[o] = fast_sigmoid(sb0[o] + sum);
    }

    // ---- Layer 1: 4 -> 8 (redundant in the pair; cheap) ----
    float h1[8];
    #pragma unroll
    for (int j = 0; j < 8; ++j) {
        float a = sb1[j];
        #pragma unroll
        for (int c = 0; c < 4; ++c) a = fmaf(h0[c], sW1[j * 4 + c], a);
        h1[j] = fast_sigmoid(a);
    }

    // ---- Layer 2: 8 -> 8 (redundant in the pair) ----
    float h2[8];
    #pragma unroll
    for (int j = 0; j < 8; ++j) {
        float a = sb2[j];
        #pragma unroll
        for (int i = 0; i < 8; ++i) a = fmaf(h1[i], sW2[j * 8 + i], a);
        h2[j] = fast_sigmoid(a);
    }

    // ---- Layer 3: 8 -> 32, split 16 outputs per lane; NT stores ----
    const long long row = row0 + r;
    if (row < batch) {
        v4f* op = reinterpret_cast<v4f*>(out + (size_t)row * OUT_DIM) + (h << 2);
        #pragma unroll
        for (int q = 0; q < 4; ++q) {
            const int obase = (h << 4) + (q << 2);
            float o4[4];
            #pragma unroll
            for (int t = 0; t < 4; ++t) {
                const int oidx = obase + t;
                float a = sb3[oidx];
                #pragma unroll
                for (int j = 0; j < 8; ++j)
                    a = fmaf(h2[j], sW3[oidx * 8 + j], a);
                o4[t] = fast_sigmoid(a);
            }
            v4f v = {o4[0], o4[1], o4[2], o4[3]};
            __builtin_nontemporal_store(v, op + q);
        }
    }
}

extern "C" void kernel_launch(void* const* d_in, const int* in_sizes, int n_in,
                              void* d_out, int out_size, void* d_ws, size_t ws_size,
                              hipStream_t stream) {
    const float* x  = (const float*)d_in[0];
    const float* W0 = (const float*)d_in[1];
    const float* b0 = (const float*)d_in[2];
    const float* W1 = (const float*)d_in[3];
    const float* b1 = (const float*)d_in[4];
    const float* W2 = (const float*)d_in[5];
    const float* b2 = (const float*)d_in[6];
    const float* W3 = (const float*)d_in[7];
    const float* b3 = (const float*)d_in[8];
    float* out = (float*)d_out;

    const int batch  = in_sizes[0] / IN_DIM;  // 1,000,000
    const int blocks = (batch + ROWS_PER_BLOCK - 1) / ROWS_PER_BLOCK;

    mlp4_kernel<<<blocks, THREADS, 0, stream>>>(x, W0, b0, W1, b1,
                                                W2, b2, W3, b3, out, batch);
}

// Round 8
// 87.859 us; speedup vs baseline: 1.2777x; 1.1785x over previous
//
#include <hip/hip_runtime.h>
#include <cstdint>

// 4-layer MLP: [B,64] -> 4 -> 8 -> 8 -> 32, sigmoid each layer. All f32.
//
// R1 (145us): per-thread row reads, VGPR=32 -> loads SERIALIZED (not L1
//             thrash as first thought — key model correction from R7).
// R2-R7 (95-184us): LDS-staging variants via global_load_lds; all plateau
//             at 0.9-2 TB/s with nothing saturated. R7 counters: 4M LDS
//             bank conflicts (bad swizzle: lane pairs alias bank groups)
//             and WRITE 205 MB vs 128 (NT stores defeat L2 write-merge).
// R8: NO LDS for x. Direct-to-VGPR: lane pair (2r,2r+1) splits row r;
//     each lane loads its own contiguous 128 B as 8 independent dwordx4
//     (all in flight, one wait — what R1 lacked). Weights in LDS with
//     uniform/2-way addresses (free broadcast). L0 pair-split + shfl_xor
//     reduce; mids x2-redundant (VALU is ~9us chip-wide, don't care);
//     L3 split 16 outs/lane. Plain stores (L2 merges). No x barriers.

#define IN_DIM 64
#define OUT_DIM 32
#define THREADS 256
#define ROWS_PER_BLOCK 128   // 4 waves x 32 rows

__device__ __forceinline__ float fast_sigmoid(float z) {
    float e = __expf(-z);
    return __builtin_amdgcn_rcpf(1.0f + e);
}

__global__ __launch_bounds__(THREADS) void mlp4_kernel(
    const float* __restrict__ x,
    const float* __restrict__ W0, const float* __restrict__ b0,
    const float* __restrict__ W1, const float* __restrict__ b1,
    const float* __restrict__ W2, const float* __restrict__ b2,
    const float* __restrict__ W3, const float* __restrict__ b3,
    float* __restrict__ out, int batch)
{
    // Weights/biases only (~2.6 KB LDS -> occupancy unconstrained by LDS).
    __shared__ float sW0[4 * 64];
    __shared__ float sb0[4];
    __shared__ float sW1[8 * 4];
    __shared__ float sb1[8];
    __shared__ float sW2[8 * 8];
    __shared__ float sb2[8];
    __shared__ float sW3[32 * 8];
    __shared__ float sb3[32];

    const int tid = threadIdx.x;
    sW0[tid] = W0[tid];
    sW3[tid] = W3[tid];
    if (tid < 64) sW2[tid] = W2[tid];
    if (tid < 32) { sW1[tid] = W1[tid]; sb3[tid] = b3[tid]; }
    if (tid < 8)  { sb1[tid] = b1[tid]; sb2[tid] = b2[tid]; }
    if (tid < 4)  { sb0[tid] = b0[tid]; }
    __syncthreads();

    const int lane = tid & 63;
    const int wv   = tid >> 6;
    const int r    = lane >> 1;          // wave-local row 0..31
    const int h    = lane & 1;           // row half: cols [32h, 32h+32)

    const long long row  = (long long)blockIdx.x * ROWS_PER_BLOCK + (wv << 5) + r;
    const bool     valid = row < batch;
    const long long lrow = valid ? row : (long long)(batch - 1);  // clamp loads

    // ---- Load my half-row: 8 independent dwordx4 (128 B contiguous) ----
    const float4* xp = reinterpret_cast<const float4*>(x + lrow * IN_DIM) + (h << 3);
    float4 xv[8];
    #pragma unroll
    for (int k = 0; k < 8; ++k) xv[k] = xp[k];

    // ---- Layer 0: 64 -> 4, split across the lane pair ----
    const float4* w0v = reinterpret_cast<const float4*>(sW0);
    float h0[4];
    #pragma unroll
    for (int o = 0; o < 4; ++o) {
        float a = 0.f;
        #pragma unroll
        for (int k = 0; k < 8; ++k) {
            const float4 wv4 = w0v[o * 16 + (h << 3) + k];  // 2 addrs/instr = free
            a = fmaf(xv[k].x, wv4.x, a);
            a = fmaf(xv[k].y, wv4.y, a);
            a = fmaf(xv[k].z, wv4.z, a);
            a = fmaf(xv[k].w, wv4.w, a);
        }
        const float sum = a + __shfl_xor(a, 1, 64);         // pair-reduce
        h0[o] = fast_sigmoid(sb0[o] + sum);
    }

    // ---- Layer 1: 4 -> 8 (pair-redundant; uniform LDS reads) ----
    float h1[8];
    #pragma unroll
    for (int j = 0; j < 8; ++j) {
        float a = sb1[j];
        #pragma unroll
        for (int c = 0; c < 4; ++c) a = fmaf(h0[c], sW1[j * 4 + c], a);
        h1[j] = fast_sigmoid(a);
    }

    // ---- Layer 2: 8 -> 8 (pair-redundant) ----
    float h2[8];
    #pragma unroll
    for (int j = 0; j < 8; ++j) {
        float a = sb2[j];
        #pragma unroll
        for (int i = 0; i < 8; ++i) a = fmaf(h1[i], sW2[j * 8 + i], a);
        h2[j] = fast_sigmoid(a);
    }

    // ---- Layer 3: 8 -> 32, 16 outputs per lane; plain float4 stores ----
    if (valid) {
        float4* op = reinterpret_cast<float4*>(out + (size_t)row * OUT_DIM) + (h << 2);
        #pragma unroll
        for (int q = 0; q < 4; ++q) {
            float o4[4];
            #pragma unroll
            for (int t = 0; t < 4; ++t) {
                const int oidx = (h << 4) + (q << 2) + t;
                float a = sb3[oidx];
                #pragma unroll
                for (int j = 0; j < 8; ++j)
                    a = fmaf(h2[j], sW3[oidx * 8 + j], a);
                o4[t] = fast_sigmoid(a);
            }
            op[q] = make_float4(o4[0], o4[1], o4[2], o4[3]);
        }
    }
}

extern "C" void kernel_launch(void* const* d_in, const int* in_sizes, int n_in,
                              void* d_out, int out_size, void* d_ws, size_t ws_size,
                              hipStream_t stream) {
    const float* x  = (const float*)d_in[0];
    const float* W0 = (const float*)d_in[1];
    const float* b0 = (const float*)d_in[2];
    const float* W1 = (const float*)d_in[3];
    const float* b1 = (const float*)d_in[4];
    const float* W2 = (const float*)d_in[5];
    const float* b2 = (const float*)d_in[6];
    const float* W3 = (const float*)d_in[7];
    const float* b3 = (const float*)d_in[8];
    float* out = (float*)d_out;

    const int batch  = in_sizes[0] / IN_DIM;  // 1,000,000
    const int blocks = (batch + ROWS_PER_BLOCK - 1) / ROWS_PER_BLOCK;

    mlp4_kernel<<<blocks, THREADS, 0, stream>>>(x, W0, b0, W1, b1,
                                                W2, b2, W3, b3, out, batch);
}